// Round 4
// baseline (721.419 us; speedup 1.0000x reference)
//
#include <hip/hip_runtime.h>
#include <hip/hip_bf16.h>

typedef __bf16 bf16;
typedef __attribute__((ext_vector_type(4))) int intx4;
typedef __attribute__((ext_vector_type(4))) float floatx4;

__device__ __forceinline__ float b2f(unsigned short u) {
  union { unsigned int i; float f; } v; v.i = ((unsigned int)u) << 16; return v.f;
}

__device__ __forceinline__ void async_copy16(const void* g, void* l) {
  __builtin_amdgcn_global_load_lds((__attribute__((address_space(1))) void*)(g),
                                   (__attribute__((address_space(3))) void*)(l),
                                   16, 0, 0);
}

__device__ __forceinline__ float warp_sum(float v) {
  #pragma unroll
  for (int off = 32; off > 0; off >>= 1) v += __shfl_xor(v, off, 64);
  return v;
}
__device__ __forceinline__ float warp_max(float v) {
  #pragma unroll
  for (int off = 32; off > 0; off >>= 1) v = fmaxf(v, __shfl_xor(v, off, 64));
  return v;
}

// exact-erf GELU via A&S 7.1.26 (|eps| <= 1.5e-7), hw rcp + exp
__device__ __forceinline__ float gelu_fast(float v) {
  const float a = fabsf(v) * 0.70710678118654752440f;
  const float t = __builtin_amdgcn_rcpf(fmaf(0.3275911f, a, 1.0f));
  const float e = __expf(-a * a);
  float p = fmaf(1.061405429f, t, -1.453152027f);
  p = fmaf(p, t, 1.421413741f);
  p = fmaf(p, t, -0.284496736f);
  p = fmaf(p, t, 0.254829592f);
  float erfa = fmaf(-p * t, e, 1.0f);          // erf(|v|/sqrt2)
  erfa = copysignf(erfa, v);
  return 0.5f * v * (1.0f + erfa);
}

__device__ __forceinline__ void load4(const float* p, float* v) {
  float4 u = *(const float4*)p;
  v[0] = u.x; v[1] = u.y; v[2] = u.z; v[3] = u.w;
}
__device__ __forceinline__ void load4(const bf16* p, float* v) {
  ushort4 u = *(const ushort4*)p;
  v[0] = b2f(u.x); v[1] = b2f(u.y); v[2] = b2f(u.z); v[3] = b2f(u.w);
}

// ---------------- weight absmean (per-tensor, fp32 input) ----------------
__global__ __launch_bounds__(256) void absmean_partial(const float* __restrict__ w, int n,
                                                       float* __restrict__ partial) {
  const int tid = threadIdx.x;
  const int lane = tid & 63, wave = tid >> 6;
  float s = 0.f;
  for (size_t i = ((size_t)blockIdx.x * 256 + tid) * 4; i < (size_t)n;
       i += (size_t)256 * 256 * 4) {
    float4 u = *(const float4*)(w + i);
    s += fabsf(u.x) + fabsf(u.y) + fabsf(u.z) + fabsf(u.w);
  }
  __shared__ float red[4];
  s = warp_sum(s);
  if (lane == 0) red[wave] = s;
  __syncthreads();
  if (tid == 0) partial[blockIdx.x] = red[0] + red[1] + red[2] + red[3];
}

// scales: [0]=s_w1 (quant), [1]=dq_w1, [2]=s_w2, [3]=dq_w2
__global__ __launch_bounds__(256) void finalize_scales(const float* __restrict__ p1,
                                                       const float* __restrict__ p2,
                                                       float inv_n1, float inv_n2,
                                                       float* __restrict__ scales) {
  const int tid = threadIdx.x;
  const int lane = tid & 63, wave = tid >> 6;
  float a = p1[tid], b = p2[tid];
  a = warp_sum(a); b = warp_sum(b);
  __shared__ float red[8];
  if (lane == 0) { red[wave] = a; red[4 + wave] = b; }
  __syncthreads();
  if (tid == 0) {
    float m1 = fmaxf((red[0] + red[1] + red[2] + red[3]) * inv_n1, 1e-5f);
    float m2 = fmaxf((red[4] + red[5] + red[6] + red[7]) * inv_n2, 1e-5f);
    scales[0] = 1.0f / m1; scales[1] = m1;
    scales[2] = 1.0f / m2; scales[3] = m2;
  }
}

// ternarize fp32 weights -> int8 {-1,0,1}
__global__ __launch_bounds__(256) void quant_w(const float* __restrict__ w,
                                               signed char* __restrict__ wq,
                                               const float* __restrict__ sptr, int n) {
  const int i4 = (blockIdx.x * 256 + threadIdx.x) * 4;
  if (i4 >= n) return;
  const float s = *sptr;
  float4 u = *(const float4*)(w + i4);
  char4 o;
  o.x = (signed char)fminf(fmaxf(rintf(u.x * s), -1.f), 1.f);
  o.y = (signed char)fminf(fmaxf(rintf(u.y * s), -1.f), 1.f);
  o.z = (signed char)fminf(fmaxf(rintf(u.z * s), -1.f), 1.f);
  o.w = (signed char)fminf(fmaxf(rintf(u.w * s), -1.f), 1.f);
  *(char4*)(wq + i4) = o;
}

// ---------------- [gelu] + layernorm + per-row int8 quant ----------------
// one block per row; q may alias x rows (in-place): row fully read into regs
// before first barrier, written after second. px = input pitch (XT elems),
// pq = output pitch (bytes).
template <int D, bool GELU, typename XT>
__global__ __launch_bounds__(256) void ln_quant_kernel(const XT* __restrict__ x,
                                                       const float* __restrict__ gam,
                                                       const float* __restrict__ bet,
                                                       signed char* __restrict__ q,
                                                       float* __restrict__ rdq,
                                                       int px, int pq) {
  constexpr int NC = D / 1024;
  const int tid = threadIdx.x;
  const int lane = tid & 63, wave = tid >> 6;
  const size_t xbase = (size_t)blockIdx.x * px;
  const size_t qbase = (size_t)blockIdx.x * pq;
  float y[NC * 4];
  float s = 0.f, ss = 0.f;
  #pragma unroll
  for (int c = 0; c < NC; ++c) {
    const int idx = (c * 256 + tid) * 4;
    float v[4];
    load4(x + xbase + idx, v);
    #pragma unroll
    for (int j = 0; j < 4; ++j) {
      float vv = GELU ? gelu_fast(v[j]) : v[j];
      y[c * 4 + j] = vv; s += vv; ss += vv * vv;
    }
  }
  __shared__ float red[12];
  float sw = warp_sum(s), qw = warp_sum(ss);
  if (lane == 0) { red[wave] = sw; red[4 + wave] = qw; }
  __syncthreads();
  const float inv_d = 1.0f / (float)D;
  const float mu = (red[0] + red[1] + red[2] + red[3]) * inv_d;
  const float var = (red[4] + red[5] + red[6] + red[7]) * inv_d - mu * mu;
  const float rstd = rsqrtf(var + 1e-5f);
  float amax = 0.f;
  #pragma unroll
  for (int c = 0; c < NC; ++c) {
    const int idx = (c * 256 + tid) * 4;
    float4 gv = *(const float4*)(gam + idx);
    float4 bv = *(const float4*)(bet + idx);
    float gg[4] = {gv.x, gv.y, gv.z, gv.w};
    float bb[4] = {bv.x, bv.y, bv.z, bv.w};
    #pragma unroll
    for (int j = 0; j < 4; ++j) {
      float yy = (y[c * 4 + j] - mu) * rstd * gg[j] + bb[j];
      y[c * 4 + j] = yy;
      amax = fmaxf(amax, fabsf(yy));
    }
  }
  float wm = warp_max(amax);
  if (lane == 0) red[8 + wave] = wm;
  __syncthreads();
  const float am = fmaxf(fmaxf(fmaxf(red[8], red[9]), fmaxf(red[10], red[11])), 1e-5f);
  const float sc = 127.0f / am;
  #pragma unroll
  for (int c = 0; c < NC; ++c) {
    const int idx = (c * 256 + tid) * 4;
    char4 o;
    o.x = (signed char)fminf(fmaxf(rintf(y[c * 4 + 0] * sc), -128.f), 127.f);
    o.y = (signed char)fminf(fmaxf(rintf(y[c * 4 + 1] * sc), -128.f), 127.f);
    o.z = (signed char)fminf(fmaxf(rintf(y[c * 4 + 2] * sc), -128.f), 127.f);
    o.w = (signed char)fminf(fmaxf(rintf(y[c * 4 + 3] * sc), -128.f), 127.f);
    *(char4*)(q + qbase + idx) = o;
  }
  if (tid == 0) rdq[blockIdx.x] = am * (1.0f / 127.0f);
}

// ---------------- int8 GEMM, 256x256 tile, read-ahead 8-phase ----------------
// C[M,N] = A[M,K] * B[N,K]^T, mfma_i32_16x16x64_i8. 512 thr = 8 waves (2M x 4N),
// per-wave 128x64. BK=128B = 2 k-slots. LDS 128KB: [buf2][Aks0|Aks1|Bks0|Bks1].
// Round-4 change: ds_reads issued ONE PHASE AHEAD into alternating reg sets
// (aA/aB, bA/bB) so the LDS pipe (~2300 cy/CU/tile) overlaps the MFMA pipe
// (~2600 cy/CU/tile) instead of serializing with it. Compiler inserts the
// counted lgkmcnt waits from register deps; sched_barrier(0) pins issue
// clusters. Two vm-sync points per tile: vmcnt(2)+bar mid-tile (ks1 landed),
// vmcnt(4)+bar at boundary (next ks0 landed) — never drains to 0 mid-loop.
// Per-tile reg-set/phase map (ks = k-slot, mh = m-half):
//   boundary: issue aA<-A(mh0,ks0), bA<-B(ks0)
//   ph0: issue aB<-A(mh1,ks0); stage Aks0(t+1); MFMA(mh0: aA,bA)
//   ph1: vmcnt(2)+bar; issue aA<-A(mh0,ks1), bB<-B(ks1); stage Bks0(t+1);
//        MFMA(mh1: aB,bA)
//   ph2: issue aB<-A(mh1,ks1); stage Aks1(t+1); MFMA(mh0: aA,bB)
//   ph3: stage Bks1(t+1); MFMA(mh1: aB,bB); vmcnt(4)+bar
// Outstanding-load invariant at tile entry: 4 (= ks1(t) halves). Last tile
// clamps staging to in-bounds (dead data) so the counts stay exact.

#define ISSUE_A(DST, MH, KS, BUF)                                            \
  _Pragma("unroll") for (int mi = 0; mi < 4; ++mi) {                         \
    DST[mi] = *(const intx4*)&lds[(BUF) * 65536 + (KS) * 16384 + aoff +      \
                                  ((MH) * 4 + mi) * 1024];                   \
  }

#define ISSUE_B(DST, KS, BUF)                                                \
  _Pragma("unroll") for (int ni = 0; ni < 4; ++ni) {                         \
    DST[ni] = *(const intx4*)&lds[(BUF) * 65536 + 32768 + (KS) * 16384 +     \
                                  boff + ni * 1024];                         \
  }

#define MFMA_CL(MH, AR, BR)                                                  \
  __builtin_amdgcn_s_setprio(1);                                             \
  _Pragma("unroll") for (int mi = 0; mi < 4; ++mi) {                         \
    _Pragma("unroll") for (int ni = 0; ni < 4; ++ni) {                       \
      acc[(MH) * 4 + mi][ni] = __builtin_amdgcn_mfma_i32_16x16x64_i8(        \
          AR[mi], BR[ni], acc[(MH) * 4 + mi][ni], 0, 0, 0);                  \
    }                                                                        \
  }                                                                          \
  __builtin_amdgcn_s_setprio(0);

#define TILE(T, BUF, LAST)                                                   \
  do {                                                                       \
    const int ts_ = (LAST) ? (T) : (T) + 1;                                  \
    /* ph0 */                                                                \
    ISSUE_A(aB, 1, 0, BUF);                                                  \
    __builtin_amdgcn_sched_barrier(0);                                       \
    stageA(ts_, 0, (BUF) ^ 1);                                               \
    __builtin_amdgcn_s_barrier();                                            \
    MFMA_CL(0, aA, bA);                                                      \
    __builtin_amdgcn_s_barrier();                                            \
    /* ph1 */                                                                \
    asm volatile("s_waitcnt vmcnt(2)" ::: "memory");                         \
    __builtin_amdgcn_s_barrier();                                            \
    ISSUE_A(aA, 0, 1, BUF);                                                  \
    ISSUE_B(bB, 1, BUF);                                                     \
    __builtin_amdgcn_sched_barrier(0);                                       \
    stageB(ts_, 0, (BUF) ^ 1);                                               \
    MFMA_CL(1, aB, bA);                                                      \
    __builtin_amdgcn_s_barrier();                                            \
    /* ph2 */                                                                \
    ISSUE_A(aB, 1, 1, BUF);                                                  \
    __builtin_amdgcn_sched_barrier(0);                                       \
    stageA(ts_, 1, (BUF) ^ 1);                                               \
    __builtin_amdgcn_s_barrier();                                            \
    MFMA_CL(0, aA, bB);                                                      \
    __builtin_amdgcn_s_barrier();                                            \
    /* ph3 */                                                                \
    stageB(ts_, 1, (BUF) ^ 1);                                               \
    MFMA_CL(1, aB, bB);                                                      \
    asm volatile("s_waitcnt vmcnt(4)" ::: "memory");                         \
    __builtin_amdgcn_s_barrier();                                            \
    if (!(LAST)) {                                                           \
      ISSUE_A(aA, 0, 0, (BUF) ^ 1);                                          \
      ISSUE_B(bA, 0, (BUF) ^ 1);                                             \
      __builtin_amdgcn_sched_barrier(0);                                     \
    }                                                                        \
  } while (0)

template <typename CT>
__global__ __launch_bounds__(512, 2) void gemm_i8(const signed char* __restrict__ A,
                                                  const signed char* __restrict__ B,
                                                  CT* __restrict__ C,
                                                  const float* __restrict__ rdq,
                                                  const float* __restrict__ wdq_ptr,
                                                  const float* __restrict__ bias,
                                                  int N, int KB, int lda, int ldc) {
  __shared__ __align__(16) signed char lds[131072];
  const int tid = threadIdx.x;
  const int wave = tid >> 6, lane = tid & 63;
  const int quad = lane >> 4, l16 = lane & 15;
  const int nb = N >> 8;
  // T1: consecutive tile ids -> same XCD
  const int cpx = (int)gridDim.x >> 3;
  const int wg = (int)blockIdx.x;
  const int tile = (wg & 7) * cpx + (wg >> 3);
  const int bm = tile / nb;
  const int bn = tile % nb;
  const int wm = wave >> 2, wn = wave & 3;

  // staging: per half (16KB = 1024 chunks of 16B), thread handles chunks ch0, ch1.
  // chunk ch = row*4 + slot; global slot pre-swizzled: slot ^ ((row>>1)&3),
  // and (4*row+slot)>>3 == row>>1 exactly.
  const int ch0 = wave * 128 + lane;
  const int ch1 = ch0 + 64;
  const int g0 = ((ch0 & 3) ^ ((ch0 >> 3) & 3)) * 16;
  const int g1 = ((ch1 & 3) ^ ((ch1 >> 3) & 3)) * 16;
  const signed char* a0 = A + (size_t)(bm * 256 + (ch0 >> 2)) * lda + g0;
  const signed char* a1 = A + (size_t)(bm * 256 + (ch1 >> 2)) * lda + g1;
  const signed char* b0 = B + (size_t)(bn * 256 + (ch0 >> 2)) * KB + g0;
  const signed char* b1 = B + (size_t)(bn * 256 + (ch1 >> 2)) * KB + g1;

  auto stageA = [&](int t, int ks, int b) {
    signed char* d = &lds[b * 65536 + ks * 16384 + wave * 2048];
    const int off = t * 128 + ks * 64;
    async_copy16(a0 + off, d);
    async_copy16(a1 + off, d + 1024);
  };
  auto stageB = [&](int t, int ks, int b) {
    signed char* d = &lds[b * 65536 + 32768 + ks * 16384 + wave * 2048];
    const int off = t * 128 + ks * 64;
    async_copy16(b0 + off, d);
    async_copy16(b1 + off, d + 1024);
  };

  // ds_read addressing: row = (wm*128|wn*64) + frag*16 + l16; byte = row*64 + rsl.
  // row parity bits reduce to (l16>>1)&3 for every frag (others are 0 mod 4).
  const int rsl = (quad ^ ((l16 >> 1) & 3)) * 16;
  const int aoff = (wm * 128 + l16) * 64 + rsl;  // + (MH*4+mi)*1024
  const int boff = (wn * 64 + l16) * 64 + rsl;   // + ni*1024

  intx4 acc[8][4];
  #pragma unroll
  for (int i = 0; i < 8; ++i)
    #pragma unroll
    for (int j = 0; j < 4; ++j) acc[i][j] = (intx4){0, 0, 0, 0};
  intx4 aA[4], aB[4], bA[4], bB[4];

  const float wdq = *wdq_ptr;
  const int NT = KB >> 7;  // 128B K-tiles; NT even (8 or 32)

  // prologue: tile0 all 4 halves; wait ks0, leave ks1 (4 loads) in flight
  stageA(0, 0, 0); stageB(0, 0, 0);
  stageA(0, 1, 0); stageB(0, 1, 0);
  asm volatile("s_waitcnt vmcnt(4)" ::: "memory");
  __builtin_amdgcn_s_barrier();
  ISSUE_A(aA, 0, 0, 0);
  ISSUE_B(bA, 0, 0);
  __builtin_amdgcn_sched_barrier(0);

  for (int t = 0; t < NT - 2; t += 2) {
    TILE(t, 0, false);
    TILE(t + 1, 1, false);
  }
  TILE(NT - 2, 0, false);
  TILE(NT - 1, 1, true);

  // epilogue: C/D layout col=lane&15, row=quad*4+reg (shape-determined, m121-128)
  #pragma unroll
  for (int mi = 0; mi < 8; ++mi) {
    const int rowb = bm * 256 + wm * 128 + mi * 16 + quad * 4;
    const floatx4 rd = *(const floatx4*)&rdq[rowb];
    #pragma unroll
    for (int ni = 0; ni < 4; ++ni) {
      const int col = bn * 256 + wn * 64 + ni * 16 + l16;
      const float bv = bias[col];
      #pragma unroll
      for (int r2 = 0; r2 < 4; ++r2) {
        float v = fmaf((float)acc[mi][ni][r2], rd[r2] * wdq, bv);
        C[(size_t)(rowb + r2) * ldc + col] = (CT)v;
      }
    }
  }
}

extern "C" void kernel_launch(void* const* d_in, const int* in_sizes, int n_in,
                              void* d_out, int out_size, void* d_ws, size_t ws_size,
                              hipStream_t stream) {
  (void)in_sizes; (void)n_in; (void)out_size; (void)ws_size;
  const float* x   = (const float*)d_in[0];
  const float* g1  = (const float*)d_in[1];
  const float* be1 = (const float*)d_in[2];
  const float* w1  = (const float*)d_in[3];
  const float* b1  = (const float*)d_in[4];
  const float* g2  = (const float*)d_in[5];
  const float* be2 = (const float*)d_in[6];
  const float* w2  = (const float*)d_in[7];
  const float* b2  = (const float*)d_in[8];
  float* out = (float*)d_out;

  const int BT = 8 * 4096, D = 1024, H = 4096;
  char* ws = (char*)d_ws;
  float* scales = (float*)(ws);                 // 4 floats
  float* p1     = (float*)(ws + 1024);
  float* p2     = (float*)(ws + 2048);
  float* rdq1   = (float*)(ws + 4096);          // 32768 fp32
  float* rdq2   = (float*)(ws + 4096 + 131072);
  char* big = ws + (1 << 20);
  signed char* w1q = (signed char*)(big);                 // 4 MB
  signed char* w2q = (signed char*)(big + (4 << 20));     // 4 MB
  signed char* qx1 = (signed char*)(big + (8 << 20));     // 32 MB
  bf16* h1 = (bf16*)(big + (40 << 20));                   // 256 MB -> total ~297 MB

  const int NW = H * D;
  absmean_partial<<<256, 256, 0, stream>>>(w1, NW, p1);
  absmean_partial<<<256, 256, 0, stream>>>(w2, NW, p2);
  finalize_scales<<<1, 256, 0, stream>>>(p1, p2, 1.0f / NW, 1.0f / NW, scales);
  quant_w<<<NW / 1024, 256, 0, stream>>>(w1, w1q, scales + 0, NW);
  quant_w<<<NW / 1024, 256, 0, stream>>>(w2, w2q, scales + 2, NW);

  // LN1 + act quant -> int8
  ln_quant_kernel<1024, false, float><<<BT, 256, 0, stream>>>(x, g1, be1, qx1, rdq1,
                                                              D, D);
  // GEMM1: h1(bf16) = dequant(qx1 . w1q^T) + b1   (pre-GELU; GELU fused into LN2)
  gemm_i8<bf16><<<(BT / 256) * (H / 256), 512, 0, stream>>>(
      qx1, w1q, h1, rdq1, scales + 1, b1, H, D, D, H);
  // GELU + LN2 + act quant, int8 written in-place into h1 row starts (pitch 8192 B)
  ln_quant_kernel<4096, true, bf16><<<BT, 256, 0, stream>>>(
      h1, g2, be2, (signed char*)h1, rdq2, H, 2 * H);
  // GEMM2: out(fp32) = dequant(q . w2q^T) + b2
  gemm_i8<float><<<(BT / 256) * (D / 256), 512, 0, stream>>>(
      (signed char*)h1, w2q, out, rdq2, scales + 3, b2, D, H, 2 * H, D);
}

// Round 6
// 685.625 us; speedup vs baseline: 1.0522x; 1.0522x over previous
//
#include <hip/hip_runtime.h>
#include <hip/hip_bf16.h>

typedef __bf16 bf16;
typedef __attribute__((ext_vector_type(4))) int intx4;
typedef __attribute__((ext_vector_type(4))) float floatx4;
typedef __attribute__((ext_vector_type(8))) unsigned short ushortx8;

__device__ __forceinline__ float b2f(unsigned short u) {
  union { unsigned int i; float f; } v; v.i = ((unsigned int)u) << 16; return v.f;
}

__device__ __forceinline__ void async_copy16(const void* g, void* l) {
  __builtin_amdgcn_global_load_lds((__attribute__((address_space(1))) void*)(g),
                                   (__attribute__((address_space(3))) void*)(l),
                                   16, 0, 0);
}

__device__ __forceinline__ float warp_sum(float v) {
  #pragma unroll
  for (int off = 32; off > 0; off >>= 1) v += __shfl_xor(v, off, 64);
  return v;
}
__device__ __forceinline__ float warp_max(float v) {
  #pragma unroll
  for (int off = 32; off > 0; off >>= 1) v = fmaxf(v, __shfl_xor(v, off, 64));
  return v;
}

// exact-erf GELU via A&S 7.1.26 (|eps| <= 1.5e-7), hw rcp + exp
__device__ __forceinline__ float gelu_fast(float v) {
  const float a = fabsf(v) * 0.70710678118654752440f;
  const float t = __builtin_amdgcn_rcpf(fmaf(0.3275911f, a, 1.0f));
  const float e = __expf(-a * a);
  float p = fmaf(1.061405429f, t, -1.453152027f);
  p = fmaf(p, t, 1.421413741f);
  p = fmaf(p, t, -0.284496736f);
  p = fmaf(p, t, 0.254829592f);
  float erfa = fmaf(-p * t, e, 1.0f);          // erf(|v|/sqrt2)
  erfa = copysignf(erfa, v);
  return 0.5f * v * (1.0f + erfa);
}

// clamp+round+pack 4 floats to 4 int8 in a u32 (activation quant, [-128,127])
__device__ __forceinline__ unsigned int pack4(float a, float b, float c, float d,
                                              float sc) {
  const int ia = (int)fminf(fmaxf(rintf(a * sc), -128.f), 127.f);
  const int ib = (int)fminf(fmaxf(rintf(b * sc), -128.f), 127.f);
  const int ic = (int)fminf(fmaxf(rintf(c * sc), -128.f), 127.f);
  const int id = (int)fminf(fmaxf(rintf(d * sc), -128.f), 127.f);
  return (unsigned)(ia & 255) | ((unsigned)(ib & 255) << 8) |
         ((unsigned)(ic & 255) << 16) | ((unsigned)(id & 255) << 24);
}

// ---------------- weight absmean (both tensors in one launch) ----------------
__global__ __launch_bounds__(256) void absmean2(const float* __restrict__ w1,
                                                const float* __restrict__ w2, int n,
                                                float* __restrict__ p1,
                                                float* __restrict__ p2) {
  const int half = blockIdx.x >> 8;     // grid = 512: 0..255 -> w1, 256..511 -> w2
  const int b = blockIdx.x & 255;
  const float* __restrict__ w = half ? w2 : w1;
  const int tid = threadIdx.x;
  const int lane = tid & 63, wave = tid >> 6;
  float s = 0.f;
  for (size_t i = ((size_t)b * 256 + tid) * 4; i < (size_t)n;
       i += (size_t)256 * 256 * 4) {
    float4 u = *(const float4*)(w + i);
    s += fabsf(u.x) + fabsf(u.y) + fabsf(u.z) + fabsf(u.w);
  }
  __shared__ float red[4];
  s = warp_sum(s);
  if (lane == 0) red[wave] = s;
  __syncthreads();
  if (tid == 0) (half ? p2 : p1)[b] = red[0] + red[1] + red[2] + red[3];
}

// scales: [0]=s_w1 (quant), [1]=dq_w1, [2]=s_w2, [3]=dq_w2
__global__ __launch_bounds__(256) void finalize_scales(const float* __restrict__ p1,
                                                       const float* __restrict__ p2,
                                                       float inv_n1, float inv_n2,
                                                       float* __restrict__ scales) {
  const int tid = threadIdx.x;
  const int lane = tid & 63, wave = tid >> 6;
  float a = p1[tid], b = p2[tid];
  a = warp_sum(a); b = warp_sum(b);
  __shared__ float red[8];
  if (lane == 0) { red[wave] = a; red[4 + wave] = b; }
  __syncthreads();
  if (tid == 0) {
    float m1 = fmaxf((red[0] + red[1] + red[2] + red[3]) * inv_n1, 1e-5f);
    float m2 = fmaxf((red[4] + red[5] + red[6] + red[7]) * inv_n2, 1e-5f);
    scales[0] = 1.0f / m1; scales[1] = m1;
    scales[2] = 1.0f / m2; scales[3] = m2;
  }
}

// ternarize both fp32 weight tensors -> int8 {-1,0,1} in one launch.
// NB: weight quant clamps to [-1,1] (ternary), NOT [-128,127] — R5's bug.
__global__ __launch_bounds__(256) void quant_w2(const float* __restrict__ w1,
                                                const float* __restrict__ w2,
                                                signed char* __restrict__ q1,
                                                signed char* __restrict__ q2,
                                                const float* __restrict__ scales,
                                                int nb, int n) {
  const int bid = blockIdx.x;
  const int second = bid >= nb;
  const float* __restrict__ w = second ? w2 : w1;
  signed char* __restrict__ q = second ? q2 : q1;
  const float s = scales[second * 2];
  const int i4 = ((second ? bid - nb : bid) * 256 + (int)threadIdx.x) * 4;
  if (i4 >= n) return;
  float4 u = *(const float4*)(w + i4);
  char4 o;
  o.x = (signed char)fminf(fmaxf(rintf(u.x * s), -1.f), 1.f);
  o.y = (signed char)fminf(fmaxf(rintf(u.y * s), -1.f), 1.f);
  o.z = (signed char)fminf(fmaxf(rintf(u.z * s), -1.f), 1.f);
  o.w = (signed char)fminf(fmaxf(rintf(u.w * s), -1.f), 1.f);
  *(char4*)(q + i4) = o;
}

// ---------------- [gelu] + layernorm + per-row int8 quant ----------------
// grid-stride over rows (2048 blocks); gamma/beta hoisted to registers once per
// block; 16B vector loads; packed int8 stores. q may alias x rows (in-place):
// each row fully read into regs before its barriers, written after. px = input
// pitch (XT elems), pq = output pitch (bytes). Race note: red[0..7] (sums) and
// red[8..11] (amax) are disjoint; the two per-row barriers order all cross-row
// reuse (reader of set S in row r sits between the barriers that bound the next
// write of S in row r+1).
template <int D, bool GELU, typename XT>
__global__ __launch_bounds__(256) void ln_quant_kernel(const XT* __restrict__ x,
                                                       const float* __restrict__ gam,
                                                       const float* __restrict__ bet,
                                                       signed char* __restrict__ q,
                                                       float* __restrict__ rdq,
                                                       int px, int pq, int nrows) {
  constexpr int VE = (sizeof(XT) == 4) ? 4 : 8;   // elems per 16B load
  constexpr int NV = D / (256 * VE);
  const int tid = threadIdx.x;
  const int lane = tid & 63, wave = tid >> 6;
  float gg[NV * VE], bb[NV * VE];
  #pragma unroll
  for (int v = 0; v < NV; ++v) {
    #pragma unroll
    for (int k = 0; k < VE; k += 4) {
      const int idx = v * (256 * VE) + tid * VE + k;
      float4 gv = *(const float4*)(gam + idx);
      float4 bv = *(const float4*)(bet + idx);
      gg[v * VE + k + 0] = gv.x; gg[v * VE + k + 1] = gv.y;
      gg[v * VE + k + 2] = gv.z; gg[v * VE + k + 3] = gv.w;
      bb[v * VE + k + 0] = bv.x; bb[v * VE + k + 1] = bv.y;
      bb[v * VE + k + 2] = bv.z; bb[v * VE + k + 3] = bv.w;
    }
  }
  __shared__ float red[12];
  const float inv_d = 1.0f / (float)D;
  for (int row = blockIdx.x; row < nrows; row += gridDim.x) {
    const size_t xbase = (size_t)row * px;
    const size_t qbase = (size_t)row * pq;
    float y[NV * VE];
    float s = 0.f, ss = 0.f;
    #pragma unroll
    for (int v = 0; v < NV; ++v) {
      const int idx = v * (256 * VE) + tid * VE;
      if constexpr (sizeof(XT) == 4) {
        float4 u = *(const float4*)(x + xbase + idx);
        float vv[4] = {u.x, u.y, u.z, u.w};
        #pragma unroll
        for (int j = 0; j < 4; ++j) {
          float t = GELU ? gelu_fast(vv[j]) : vv[j];
          y[v * VE + j] = t; s += t; ss += t * t;
        }
      } else {
        ushortx8 u = *(const ushortx8*)(x + xbase + idx);
        #pragma unroll
        for (int j = 0; j < 8; ++j) {
          float t = b2f(u[j]);
          t = GELU ? gelu_fast(t) : t;
          y[v * VE + j] = t; s += t; ss += t * t;
        }
      }
    }
    float sw = warp_sum(s), qw = warp_sum(ss);
    if (lane == 0) { red[wave] = sw; red[4 + wave] = qw; }
    __syncthreads();
    const float mu = (red[0] + red[1] + red[2] + red[3]) * inv_d;
    const float var = (red[4] + red[5] + red[6] + red[7]) * inv_d - mu * mu;
    const float rstd = rsqrtf(var + 1e-5f);
    float amax = 0.f;
    #pragma unroll
    for (int i = 0; i < NV * VE; ++i) {
      float yy = (y[i] - mu) * rstd * gg[i] + bb[i];
      y[i] = yy;
      amax = fmaxf(amax, fabsf(yy));
    }
    float wm = warp_max(amax);
    if (lane == 0) red[8 + wave] = wm;
    __syncthreads();
    const float am = fmaxf(fmaxf(fmaxf(red[8], red[9]), fmaxf(red[10], red[11])), 1e-5f);
    const float sc = 127.0f / am;
    #pragma unroll
    for (int v = 0; v < NV; ++v) {
      const int idx = v * (256 * VE) + tid * VE;
      if constexpr (sizeof(XT) == 4) {
        *(unsigned int*)(q + qbase + idx) =
            pack4(y[v * VE + 0], y[v * VE + 1], y[v * VE + 2], y[v * VE + 3], sc);
      } else {
        uint2 o;
        o.x = pack4(y[v * VE + 0], y[v * VE + 1], y[v * VE + 2], y[v * VE + 3], sc);
        o.y = pack4(y[v * VE + 4], y[v * VE + 5], y[v * VE + 6], y[v * VE + 7], sc);
        *(uint2*)(q + qbase + idx) = o;
      }
    }
    if (tid == 0) rdq[row] = am * (1.0f / 127.0f);
  }
}

// ---------------- int8 GEMM, 256x256 tile, 8-phase schedule ----------------
// (R3 version, verified 678 us total; see round-3 notes. T1 XCD swizzle, T2
// both-sides involution swizzle (conflicts==0), T3/T4 counted vmcnt, T5 setprio.)

#define READ_A(MH, KS, BUF)                                                  \
  _Pragma("unroll") for (int mi = 0; mi < 4; ++mi) {                         \
    aR[mi] = *(const intx4*)&lds[(BUF) * 65536 + (KS) * 16384 + aoff +       \
                                 ((MH) * 4 + mi) * 1024];                    \
  }

#define READ_B(KS, BUF)                                                      \
  _Pragma("unroll") for (int ni = 0; ni < 4; ++ni) {                         \
    bR[ni] = *(const intx4*)&lds[(BUF) * 65536 + 32768 + (KS) * 16384 +      \
                                 boff + ni * 1024];                          \
  }

#define PHASE_MFMA(MH)                                                       \
  __builtin_amdgcn_s_barrier();                                              \
  asm volatile("s_waitcnt lgkmcnt(0)" ::: "memory");                         \
  __builtin_amdgcn_s_setprio(1);                                             \
  _Pragma("unroll") for (int mi = 0; mi < 4; ++mi) {                         \
    _Pragma("unroll") for (int ni = 0; ni < 4; ++ni) {                       \
      acc[(MH) * 4 + mi][ni] = __builtin_amdgcn_mfma_i32_16x16x64_i8(        \
          aR[mi], bR[ni], acc[(MH) * 4 + mi][ni], 0, 0, 0);                  \
    }                                                                        \
  }                                                                          \
  __builtin_amdgcn_s_setprio(0);

#define TILE_STEP(T, BUF, S1, S2, VM)                                        \
  do {                                                                       \
    READ_A(0, 0, BUF);                                                       \
    READ_B(0, BUF);                                                          \
    if (S1) { stageA((T) + 1, 1, (BUF) ^ 1); }                               \
    PHASE_MFMA(0);                                                           \
    __builtin_amdgcn_s_barrier();                                            \
    READ_A(1, 0, BUF);                                                       \
    if (S1) { stageB((T) + 1, 1, (BUF) ^ 1); }                               \
    PHASE_MFMA(1);                                                           \
    __builtin_amdgcn_s_barrier();                                            \
    READ_A(0, 1, BUF);                                                       \
    READ_B(1, BUF);                                                          \
    if (S2) { stageA((T) + 2, 0, BUF); }                                     \
    PHASE_MFMA(0);                                                           \
    __builtin_amdgcn_s_barrier();                                            \
    READ_A(1, 1, BUF);                                                       \
    if (S2) { stageB((T) + 2, 0, BUF); }                                     \
    PHASE_MFMA(1);                                                           \
    asm volatile("s_waitcnt vmcnt(" #VM ")" ::: "memory");                   \
    __builtin_amdgcn_s_barrier();                                            \
  } while (0)

template <typename CT>
__global__ __launch_bounds__(512, 2) void gemm_i8(const signed char* __restrict__ A,
                                                  const signed char* __restrict__ B,
                                                  CT* __restrict__ C,
                                                  const float* __restrict__ rdq,
                                                  const float* __restrict__ wdq_ptr,
                                                  const float* __restrict__ bias,
                                                  int N, int KB, int lda, int ldc) {
  __shared__ __align__(16) signed char lds[131072];
  const int tid = threadIdx.x;
  const int wave = tid >> 6, lane = tid & 63;
  const int quad = lane >> 4, l16 = lane & 15;
  const int nb = N >> 8;
  // T1: consecutive tile ids -> same XCD
  const int cpx = (int)gridDim.x >> 3;
  const int wg = (int)blockIdx.x;
  const int tile = (wg & 7) * cpx + (wg >> 3);
  const int bm = tile / nb;
  const int bn = tile % nb;
  const int wm = wave >> 2, wn = wave & 3;

  // staging: per half (16KB = 1024 chunks of 16B), thread handles chunks ch0, ch1.
  // chunk ch = row*4 + slot; global slot pre-swizzled: slot ^ ((row>>1)&3),
  // and (4*row+slot)>>3 == row>>1 exactly.
  const int ch0 = wave * 128 + lane;
  const int ch1 = ch0 + 64;
  const int g0 = ((ch0 & 3) ^ ((ch0 >> 3) & 3)) * 16;
  const int g1 = ((ch1 & 3) ^ ((ch1 >> 3) & 3)) * 16;
  const signed char* a0 = A + (size_t)(bm * 256 + (ch0 >> 2)) * lda + g0;
  const signed char* a1 = A + (size_t)(bm * 256 + (ch1 >> 2)) * lda + g1;
  const signed char* b0 = B + (size_t)(bn * 256 + (ch0 >> 2)) * KB + g0;
  const signed char* b1 = B + (size_t)(bn * 256 + (ch1 >> 2)) * KB + g1;

  auto stageA = [&](int t, int ks, int b) {
    signed char* d = &lds[b * 65536 + ks * 16384 + wave * 2048];
    const int off = t * 128 + ks * 64;
    async_copy16(a0 + off, d);
    async_copy16(a1 + off, d + 1024);
  };
  auto stageB = [&](int t, int ks, int b) {
    signed char* d = &lds[b * 65536 + 32768 + ks * 16384 + wave * 2048];
    const int off = t * 128 + ks * 64;
    async_copy16(b0 + off, d);
    async_copy16(b1 + off, d + 1024);
  };

  // ds_read addressing: row = (wm*128|wn*64) + (frag)*16 + l16; byte = row*64 + rsl.
  // row parity bits reduce to (l16>>1)&3 for every frag (others are 0 mod 4).
  const int rsl = (quad ^ ((l16 >> 1) & 3)) * 16;
  const int aoff = (wm * 128 + l16) * 64 + rsl;  // + (MH*4+mi)*1024
  const int boff = (wn * 64 + l16) * 64 + rsl;   // + ni*1024

  intx4 acc[8][4];
  #pragma unroll
  for (int i = 0; i < 8; ++i)
    #pragma unroll
    for (int j = 0; j < 4; ++j) acc[i][j] = (intx4){0, 0, 0, 0};
  intx4 aR[4], bR[4];

  const float wdq = *wdq_ptr;
  const int NT = KB >> 7;  // 128B K-tiles; NT even (8 or 32)

  // prologue: tile0 all 4 halves + tile1 k0 halves; leave tile1's 2 halves in flight
  stageA(0, 0, 0); stageB(0, 0, 0);
  stageA(0, 1, 0); stageB(0, 1, 0);
  stageA(1, 0, 1); stageB(1, 0, 1);
  asm volatile("s_waitcnt vmcnt(4)" ::: "memory");
  __builtin_amdgcn_s_barrier();

  for (int t = 0; t < NT - 2; t += 2) {
    TILE_STEP(t, 0, true, true, 4);
    TILE_STEP(t + 1, 1, true, true, 4);
  }
  TILE_STEP(NT - 2, 0, true, false, 0);
  TILE_STEP(NT - 1, 1, false, false, 0);

  // epilogue: C/D layout col=lane&15, row=quad*4+reg (shape-determined, m121-128)
  #pragma unroll
  for (int mi = 0; mi < 8; ++mi) {
    const int rowb = bm * 256 + wm * 128 + mi * 16 + quad * 4;
    const floatx4 rd = *(const floatx4*)&rdq[rowb];
    #pragma unroll
    for (int ni = 0; ni < 4; ++ni) {
      const int col = bn * 256 + wn * 64 + ni * 16 + l16;
      const float bv = bias[col];
      #pragma unroll
      for (int r2 = 0; r2 < 4; ++r2) {
        float v = fmaf((float)acc[mi][ni][r2], rd[r2] * wdq, bv);
        C[(size_t)(rowb + r2) * ldc + col] = (CT)v;
      }
    }
  }
}

extern "C" void kernel_launch(void* const* d_in, const int* in_sizes, int n_in,
                              void* d_out, int out_size, void* d_ws, size_t ws_size,
                              hipStream_t stream) {
  (void)in_sizes; (void)n_in; (void)out_size; (void)ws_size;
  const float* x   = (const float*)d_in[0];
  const float* g1  = (const float*)d_in[1];
  const float* be1 = (const float*)d_in[2];
  const float* w1  = (const float*)d_in[3];
  const float* b1  = (const float*)d_in[4];
  const float* g2  = (const float*)d_in[5];
  const float* be2 = (const float*)d_in[6];
  const float* w2  = (const float*)d_in[7];
  const float* b2  = (const float*)d_in[8];
  float* out = (float*)d_out;

  const int BT = 8 * 4096, D = 1024, H = 4096;
  char* ws = (char*)d_ws;
  float* scales = (float*)(ws);                 // 4 floats
  float* p1     = (float*)(ws + 1024);
  float* p2     = (float*)(ws + 2048);
  float* rdq1   = (float*)(ws + 4096);          // 32768 fp32
  float* rdq2   = (float*)(ws + 4096 + 131072);
  char* big = ws + (1 << 20);
  signed char* w1q = (signed char*)(big);                 // 4 MB
  signed char* w2q = (signed char*)(big + (4 << 20));     // 4 MB
  signed char* qx1 = (signed char*)(big + (8 << 20));     // 32 MB
  bf16* h1 = (bf16*)(big + (40 << 20));                   // 256 MB -> total ~297 MB

  const int NW = H * D;
  absmean2<<<512, 256, 0, stream>>>(w1, w2, NW, p1, p2);
  finalize_scales<<<1, 256, 0, stream>>>(p1, p2, 1.0f / NW, 1.0f / NW, scales);
  quant_w2<<<2 * (NW / 1024), 256, 0, stream>>>(w1, w2, w1q, w2q, scales,
                                                NW / 1024, NW);

  // LN1 + act quant -> int8 (grid-stride over rows)
  ln_quant_kernel<1024, false, float><<<2048, 256, 0, stream>>>(x, g1, be1, qx1, rdq1,
                                                                D, D, BT);
  // GEMM1: h1(bf16) = dequant(qx1 . w1q^T) + b1   (pre-GELU; GELU fused into LN2)
  gemm_i8<bf16><<<(BT / 256) * (H / 256), 512, 0, stream>>>(
      qx1, w1q, h1, rdq1, scales + 1, b1, H, D, D, H);
  // GELU + LN2 + act quant, int8 written in-place into h1 row starts (pitch 8192 B)
  ln_quant_kernel<4096, true, bf16><<<2048, 256, 0, stream>>>(
      h1, g2, be2, (signed char*)h1, rdq2, H, 2 * H, BT);
  // GEMM2: out(fp32) = dequant(q . w2q^T) + b2
  gemm_i8<float><<<(BT / 256) * (D / 256), 512, 0, stream>>>(
      (signed char*)h1, w2q, out, rdq2, scales + 3, b2, D, H, 2 * H, D);
}